// Round 1
// 122.793 us; speedup vs baseline: 1.1474x; 1.1474x over previous
//
#include <hip/hip_runtime.h>
#include <hip/hip_fp16.h>
#include <math.h>

// 14-qubit batched statevector sim, MFMA engine. R11 = R10 (108 us kernel) +
// B/C pass fusion: the B-phase (wires 5-9) output tiles have rows = wires
// 10-13 (mlow), and the MFMA D-register layout (col=lane&15, row=4q+reg) is
// bit-identical to the B-operand layout of v_mfma_f32_16x16x16_f16
// (col=lane&15, k=4q+reg). So the whole C pass (RX 10-13 + chain CNOTs) is
// applied in-register as D2 = U_C * D1 (two complex 16x16x16 MFMAs per tile):
//   - ext-ctrl CNOT(9,10): ctrl = wire9 = n-half -> per-half A-frag row flip
//     (row cc vs cc^15; same X-conjugation algebra as old passC's n^15).
//   - wrap CNOT(13,0): ctrl = wire13 = q>>1 (lane-const) -> i-pair swap folded
//     into the store v_perm selector (non-final) / Z0 sign fold (final).
// Pass count 11 -> 7 (L1: super(B+C); l=1..3: A + super(B+C)); F_C layout and
// passC deleted. Superpass stores go straight to F32 for the next A-pass:
// runs of 4 f16 across i (= wires 0-1):
//   pS = (8q+2j+half)*512 + 128*(wave>>1) + 4*(wave&1) + 8*(cc ^ (2j+half) ^ q)
// (verified symbolically + on concrete elements vs the old passC store).
//
// Layouts kept from R7/R8 (verified):
//   F32: phys = t*512 + ((128*(k>>3) + 8*mlow + (k&7)) ^ swz(t))
//   B-planes octet-major: re at 256*(k>>3)+8*n+(k&7), im at +1024.
//   C-planes (new, A-frag order): UCr at 16*r+k, UCi at +256, -UCi at +512.
// LDS: 65536 state + 4096 Bc + 1536 Cc + 560 angles = 71728 B (2 blocks/CU).

#define NQ 14
#define NLAYERS 4
#define NCLASSES 10
#define BLOCK 512

typedef _Float16 f16;
typedef _Float16 f16x2 __attribute__((ext_vector_type(2)));
typedef _Float16 f16x4 __attribute__((ext_vector_type(4)));
typedef _Float16 f16x8 __attribute__((ext_vector_type(8)));
typedef float f32x4 __attribute__((ext_vector_type(4)));
typedef unsigned int u32;
typedef u32 u32x2 __attribute__((ext_vector_type(2)));

__device__ __forceinline__ f32x4 mf(f16x8 a, f16x8 b, f32x4 c) {
  return __builtin_amdgcn_mfma_f32_16x16x32_f16(a, b, c, 0, 0, 0);
}
__device__ __forceinline__ f32x4 mf16(f16x4 a, f16x4 b, f32x4 c) {
  return __builtin_amdgcn_mfma_f32_16x16x16f16(a, b, c, 0, 0, 0);
}
__device__ __forceinline__ int swz(int t) { return ((t ^ (t >> 3)) & 7) << 3; }

// packed f32x4 -> f16x4 (2x v_cvt_pkrtz_f16_f32)
__device__ __forceinline__ f16x4 cvt4(f32x4 v) {
  u32x2 r;
  r[0] = __builtin_bit_cast(u32, __builtin_amdgcn_cvt_pkrtz(v[0], v[1]));
  r[1] = __builtin_bit_cast(u32, __builtin_amdgcn_cvt_pkrtz(v[2], v[3]));
  return __builtin_bit_cast(f16x4, r);
}
__device__ __forceinline__ u32 dwof(f16x4 v, int k) {
  return __builtin_bit_cast(u32x2, v)[k];
}

__device__ __forceinline__ int finv5(int n) {
  n ^= ((n >> 3) & 1) << 4;
  n ^= ((n >> 2) & 1) << 3;
  n ^= ((n >> 1) & 1) << 2;
  n ^= (n & 1) << 1;
  return n;
}
__device__ __forceinline__ int finv3(int n) {
  n ^= ((n >> 2) & 1) << 3;
  n ^= ((n >> 1) & 1) << 2;
  n ^= (n & 1) << 1;
  return n;
}

// 32x32 U (RX bits0-4 + 4-CNOT chain), pre-split: re plane [0,1024), im [1024,2048).
__device__ __forceinline__ void build32(f16* Bc, const float* qc, const float* qs,
                                        int base, int tid) {
  const float c0 = qc[base], c1 = qc[base+1], c2 = qc[base+2], c3 = qc[base+3], c4 = qc[base+4];
  const float s0 = qs[base], s1 = qs[base+1], s2 = qs[base+2], s3 = qs[base+3], s4 = qs[base+4];
#pragma unroll
  for (int e = tid; e < 1024; e += BLOCK) {
    const int n = e >> 5, k = e & 31;
    const int d = finv5(n) ^ k;
    float mag = ((d & 1) ? s0 : c0) * ((d & 2) ? s1 : c1);
    mag *= ((d & 4) ? s2 : c2) * ((d & 8) ? s3 : c3);
    mag *= ((d & 16) ? s4 : c4);
    const int t = __popc(d) & 3;
    const f16 v = (f16)((t == 1 || t == 2) ? -mag : mag);
    const int p = 256 * (k >> 3) + 8 * n + (k & 7);
    const bool isreal = !(t & 1);
    Bc[p]        = isreal ? v : (f16)0.f;
    Bc[p + 1024] = isreal ? (f16)0.f : v;
  }
}

// 16x16 U_C (RX bits0-3 + 3-chain) in A-frag order [row r'][k]:
// UCr at 16r+k, UCi at +256, -UCi at +512.
__device__ __forceinline__ void buildC2(f16* Cc, const float* qc, const float* qs,
                                        int base, int tid) {
  if (tid < 256) {
    const float c0 = qc[base], c1 = qc[base+1], c2 = qc[base+2], c3 = qc[base+3];
    const float s0 = qs[base], s1 = qs[base+1], s2 = qs[base+2], s3 = qs[base+3];
    const int rp = tid >> 4, k = tid & 15;
    const int d = finv3(rp) ^ k;
    float mag = ((d & 1) ? s0 : c0) * ((d & 2) ? s1 : c1);
    mag *= ((d & 4) ? s2 : c2) * ((d & 8) ? s3 : c3);
    const int t = __popc(d) & 3;
    const f16 v = (f16)((t == 1 || t == 2) ? -mag : mag);
    const bool isreal = !(t & 1);
    const int p = 16 * rp + k;
    Cc[p]       = isreal ? v : (f16)0.f;
    Cc[p + 256] = isreal ? (f16)0.f : v;
    Cc[p + 512] = isreal ? (f16)0.f : (f16)(-v);
  }
}

// A-pass (wires 0-4, no ext ctrl), unchanged from R10 pass32<false,false>.
__device__ __forceinline__ void passA(f16* __restrict__ reP, f16* __restrict__ imP,
                                      const f16* __restrict__ BcR, int tid) {
  const int lane = tid & 63, wave = tid >> 6;
  const int q = lane >> 4, cc = lane & 15;
  const int n0 = cc, n1 = cc | 16;
  const f16x8 br0 = *(const f16x8*)(BcR + 256 * q + 8 * n0);
  const f16x8 bi0 = *(const f16x8*)(BcR + 1024 + 256 * q + 8 * n0);
  const f16x8 br1 = *(const f16x8*)(BcR + 256 * q + 8 * n1);
  const f16x8 bi1 = *(const f16x8*)(BcR + 1024 + 256 * q + 8 * n1);
  f16x4 outR[8], outI[8];
#pragma unroll
  for (int i = 0; i < 4; ++i) {
    const int mt = wave * 4 + i;
    const int pA = mt * 512 + ((128 * q + 8 * cc) ^ swz(mt));
    const f16x8 Ar = *(const f16x8*)(reP + pA);
    const f16x8 Ai = *(const f16x8*)(imP + pA);
    const f16x8 nAi = -Ai;
    {
      f32x4 aR = {0.f,0.f,0.f,0.f}, aI = {0.f,0.f,0.f,0.f};
      aR = mf(Ar, br0, aR); aR = mf(nAi, bi0, aR);
      aI = mf(Ar, bi0, aI); aI = mf(Ai, br0, aI);
      outR[i * 2 + 0] = cvt4(aR);
      outI[i * 2 + 0] = cvt4(aI);
    }
    {
      f32x4 aR = {0.f,0.f,0.f,0.f}, aI = {0.f,0.f,0.f,0.f};
      aR = mf(Ar, br1, aR); aR = mf(nAi, bi1, aR);
      aI = mf(Ar, bi1, aI); aI = mf(Ai, br1, aI);
      outR[i * 2 + 1] = cvt4(aR);
      outI[i * 2 + 1] = cvt4(aI);
    }
  }
  __syncthreads();   // all reads done before in-place permuted writes
#pragma unroll
  for (int i = 0; i < 4; ++i) {
    const int mt = wave * 4 + i;
#pragma unroll
    for (int nt = 0; nt < 2; ++nt) {
      const int n5 = nt * 16 + cc;
      const int pS = n5 * 512 +
          ((128 * (2 * (mt & 1) + (q >> 1)) + 8 * (mt >> 1) + 4 * (q & 1)) ^ swz(n5));
      *(f16x4*)(reP + pS) = outR[i * 2 + nt];
      *(f16x4*)(imP + pS) = outI[i * 2 + nt];
    }
  }
}

// Fused B+C superpass: 5-wire GEMM (wires 5-9, ext-ctrl CNOT(4,5) via wave>=4
// row flip) followed by in-register 4-wire C gate (wires 10-13) as complex
// 16x16x16 MFMAs: prior D (col=lane&15,row=4q+reg) IS the next B-operand
// (col=lane&15,k=4q+reg). FINAL: fused readout from the C accumulators.
template<bool FINAL>
__device__ __forceinline__ void superBC(f16* __restrict__ reP, f16* __restrict__ imP,
                                        const f16* __restrict__ BcR,
                                        const f16* __restrict__ Cc,
                                        int tid, float* __restrict__ zloc) {
  const int lane = tid & 63, wave = tid >> 6;
  const int q = lane >> 4, cc = lane & 15;
  int n0 = cc, n1 = cc | 16;
  if (wave >= 4) { n0 ^= 31; n1 ^= 31; }   // ext-ctrl CNOT(4,5): wire4 = mt bit4
  const f16x8 br0 = *(const f16x8*)(BcR + 256 * q + 8 * n0);
  const f16x8 bi0 = *(const f16x8*)(BcR + 1024 + 256 * q + 8 * n0);
  const f16x8 br1 = *(const f16x8*)(BcR + 256 * q + 8 * n1);
  const f16x8 bi1 = *(const f16x8*)(BcR + 1024 + 256 * q + 8 * n1);
  // U_C A-frags, both ext-ctrl(9,10) variants (ctrl = wire9 = half -> row^15)
  const int r0 = 16 * cc + 4 * q, r1 = 16 * (cc ^ 15) + 4 * q;
  const f16x4 ucr0 = *(const f16x4*)(Cc + r0);
  const f16x4 uci0 = *(const f16x4*)(Cc + 256 + r0);
  const f16x4 ucn0 = *(const f16x4*)(Cc + 512 + r0);
  const f16x4 ucr1 = *(const f16x4*)(Cc + r1);
  const f16x4 uci1 = *(const f16x4*)(Cc + 256 + r1);
  const f16x4 ucn1 = *(const f16x4*)(Cc + 512 + r1);

  f16x4 accR[4][2], accI[4][2];   // [i][half] (non-final)
  float z0b = 0.f, z1b = 0.f, z9b = 0.f, zA = 0.f, zB = 0.f, pt = 0.f;
#pragma unroll
  for (int i = 0; i < 4; ++i) {
    const int mt = wave * 4 + i;
    const int pA = mt * 512 + ((128 * q + 8 * cc) ^ swz(mt));
    const f16x8 Ar = *(const f16x8*)(reP + pA);
    const f16x8 Ai = *(const f16x8*)(imP + pA);
    const f16x8 nAi = -Ai;
#pragma unroll
    for (int h = 0; h < 2; ++h) {
      const f16x8 br = h ? br1 : br0;
      const f16x8 bi = h ? bi1 : bi0;
      f32x4 aR = {0.f,0.f,0.f,0.f}, aI = {0.f,0.f,0.f,0.f};
      aR = mf(Ar, br, aR); aR = mf(nAi, bi, aR);
      aI = mf(Ar, bi, aI); aI = mf(Ai, br, aI);
      const f16x4 s1r = cvt4(aR), s1i = cvt4(aI);
      const f16x4 ur = h ? ucr1 : ucr0;
      const f16x4 ui = h ? uci1 : uci0;
      const f16x4 un = h ? ucn1 : ucn0;
      f32x4 cR = {0.f,0.f,0.f,0.f}, cI = {0.f,0.f,0.f,0.f};
      cR = mf16(ur, s1r, cR); cR = mf16(un, s1i, cR);   // UCr*S1r - UCi*S1i
      cI = mf16(ui, s1r, cI); cI = mf16(ur, s1i, cI);   // UCi*S1r + UCr*S1i
      if constexpr (FINAL) {
        // element (wires): 0-1=i bits [+wrap], 2-4=wave bits, 5-8=cc bits,
        // 9=h, 10-11=j bits, 12-13=q bits; wrap: wire0 ^= (q>>1).
        const float p0 = cR[0]*cR[0] + cI[0]*cI[0];
        const float p1 = cR[1]*cR[1] + cI[1]*cI[1];
        const float p2 = cR[2]*cR[2] + cI[2]*cI[2];
        const float p3 = cR[3]*cR[3] + cI[3]*cI[3];
        const float ps = (p0 + p1) + (p2 + p3);
        zA += (p0 - p1) + (p2 - p3);          // Z10 (j bit0)
        zB += (p0 + p1) - (p2 + p3);          // Z11 (j bit1)
        z0b += (i & 1) ? -ps : ps;
        z1b += (i & 2) ? -ps : ps;
        z9b += h ? -ps : ps;
        pt  += ps;
      } else {
        accR[i][h] = cvt4(cR);
        accI[i][h] = cvt4(cI);
      }
    }
  }
  if constexpr (FINAL) {
    zloc[0]  += (q & 2) ? -z0b : z0b;   // wrap CNOT(13,0) sign fold
    zloc[1]  += z1b;
    zloc[2]  += (wave & 1) ? -pt : pt;
    zloc[3]  += (wave & 2) ? -pt : pt;
    zloc[4]  += (wave & 4) ? -pt : pt;
    zloc[5]  += (cc & 1) ? -pt : pt;
    zloc[6]  += (cc & 2) ? -pt : pt;
    zloc[7]  += (cc & 4) ? -pt : pt;
    zloc[8]  += (cc & 8) ? -pt : pt;
    zloc[9]  += z9b;
    zloc[10] += zA;
    zloc[11] += zB;
    zloc[12] += (q & 1) ? -pt : pt;
    zloc[13] += (q & 2) ? -pt : pt;
  } else {
    __syncthreads();   // all reads done before in-place permuted writes
    // run (j,h) = f16x4 over i=0..3 (wires 0-1); wrap CNOT(13,0): lanes with
    // q>=2 swap i0<->i1, i2<->i3 (folded into the v_perm selector).
    const u32 selLo = (q & 2) ? 0x01000504u : 0x05040100u;
    const u32 selHi = (q & 2) ? 0x03020706u : 0x07060302u;
    const int ibase = 128 * (wave >> 1) + 4 * (wave & 1);
#pragma unroll
    for (int h = 0; h < 2; ++h) {
#pragma unroll
      for (int j = 0; j < 4; ++j) {
        const int pS = (8 * q + 2 * j + h) * 512 + ibase +
                       8 * (cc ^ (2 * j + h) ^ q);
        const int dj = j >> 1;
        const u32 sel = (j & 1) ? selHi : selLo;
        u32x2 vr, vi;
        vr[0] = __builtin_amdgcn_perm(dwof(accR[1][h], dj), dwof(accR[0][h], dj), sel);
        vr[1] = __builtin_amdgcn_perm(dwof(accR[3][h], dj), dwof(accR[2][h], dj), sel);
        vi[0] = __builtin_amdgcn_perm(dwof(accI[1][h], dj), dwof(accI[0][h], dj), sel);
        vi[1] = __builtin_amdgcn_perm(dwof(accI[3][h], dj), dwof(accI[2][h], dj), sel);
        *(u32x2*)(reP + pS) = vr;
        *(u32x2*)(imP + pS) = vi;
      }
    }
  }
}

__global__ __launch_bounds__(BLOCK, 4) void qsim_kernel(
    const float* __restrict__ x, const float* __restrict__ qp,
    const float* __restrict__ fcw, const float* __restrict__ fcb,
    float* __restrict__ out) {
  extern __shared__ unsigned char smem[];
  f16* reP = (f16*)smem;                    // [16384]
  f16* imP = reP + 16384;                   // [16384]
  f16* Bc  = imP + 16384;                   // [2048] re+im planes (aliased scratch)
  f16* Cc  = Bc + 2048;                     // [768] U_C A-frag planes
  float* qc = (float*)(Cc + 768);           // [56]
  float* qs = qc + 56;                      // [56]
  float* xc = qs + 56;                      // [14]
  float* xs = xc + 14;                      // [14]

  const int b = blockIdx.x;
  const int tid = threadIdx.x;

  // ---- angles ----
  if (tid < NQ) {
    float sv, cv; sincosf(0.5f * x[b * NQ + tid], &sv, &cv);
    xc[tid] = cv; xs[tid] = sv;
  } else if (tid >= 64 && tid < 64 + NLAYERS * NQ) {
    const int k = tid - 64;
    float sv, cv; sincosf(0.5f * qp[k], &sv, &cv);
    qc[k] = cv; qs[k] = sv;
  }
  __syncthreads();

  // ---- closed-form state at L1-B entry (scratch aliases Bc) ----
  float* Flo  = (float*)Bc;         // [32]
  float* psi  = Flo + 32;           // [32]
  float* PsiR = psi + 32;           // [32]
  float* PsiI = PsiR + 32;          // [32]
  if (tid < 32) {
    float f = 1.f;
#pragma unroll
    for (int j = 0; j < 5; ++j) f *= ((tid >> j) & 1) ? xs[5 + j] : xc[5 + j];
    Flo[tid] = f;
  } else if (tid < 64) {
    const int k = tid - 32;
    float f = 1.f;
#pragma unroll
    for (int j = 0; j < 5; ++j) f *= ((k >> j) & 1) ? xs[j] : xc[j];
    psi[k] = f;
  }
  __syncthreads();
  if (tid < 32) {   // Psi = U_L1A * psi
    const float c0 = qc[0], c1 = qc[1], c2 = qc[2], c3 = qc[3], c4 = qc[4];
    const float s0 = qs[0], s1 = qs[1], s2 = qs[2], s3 = qs[3], s4 = qs[4];
    const int a = finv5(tid);
    float ar = 0.f, ai = 0.f;
    for (int k = 0; k < 32; ++k) {
      const int d = a ^ k;
      float mag = ((d & 1) ? s0 : c0) * ((d & 2) ? s1 : c1);
      mag *= ((d & 4) ? s2 : c2) * ((d & 8) ? s3 : c3);
      mag *= ((d & 16) ? s4 : c4);
      mag *= psi[k];
      const int t = __popc(d) & 3;
      if (t == 0) ar += mag; else if (t == 1) ai -= mag;
      else if (t == 2) ar -= mag; else ai += mag;
    }
    PsiR[tid] = ar; PsiI[tid] = ai;
  }
  __syncthreads();
  {  // state at L1-B entry: amp(e = tid*32 + k) -> F32 layout
    float fhi = 1.f;
#pragma unroll
    for (int j = 0; j < 4; ++j) fhi *= ((tid >> j) & 1) ? xs[10 + j] : xc[10 + j];
    const float cr = fhi * PsiR[tid >> 4], ci = fhi * PsiI[tid >> 4];
    const int t = tid >> 4;
    const int sz = swz(t);
    float Fl[32];
#pragma unroll
    for (int j = 0; j < 32; ++j) Fl[j] = Flo[j];
    __syncthreads();   // scratch reads done; Bc free for builds
#pragma unroll
    for (int kb = 0; kb < 4; ++kb) {
      f16x8 hr, hi;
#pragma unroll
      for (int j = 0; j < 8; ++j) {
        const float F = Fl[8 * kb + j];
        hr[j] = (f16)(F * cr);
        hi[j] = (f16)(F * ci);
      }
      const int pb = t * 512 + ((128 * kb + 8 * (tid & 15)) ^ sz);
      *(f16x8*)(reP + pb) = hr;
      *(f16x8*)(imP + pb) = hi;
    }
  }
  build32(Bc, qc, qs, 0 * NQ + 5, tid);    // U(L1-B)
  buildC2(Cc, qc, qs, 0 * NQ + 10, tid);   // U_C(L1)
  __syncthreads();

  // ---- 7 GEMM passes (L1: B+C fused; l=1..3: A + fused B+C) ----
  superBC<false>(reP, imP, Bc, Cc, tid, nullptr);   __syncthreads();
#pragma unroll
  for (int l = 1; l < NLAYERS; ++l) {
    build32(Bc, qc, qs, l * NQ + 0, tid);           __syncthreads();
    passA(reP, imP, Bc, tid);                       __syncthreads();
    build32(Bc, qc, qs, l * NQ + 5, tid);
    buildC2(Cc, qc, qs, l * NQ + 10, tid);
    __syncthreads();
    if (l < NLAYERS - 1) {
      superBC<false>(reP, imP, Bc, Cc, tid, nullptr); __syncthreads();
    }
  }

  float zloc[NQ];
#pragma unroll
  for (int w = 0; w < NQ; ++w) zloc[w] = 0.f;
  superBC<true>(reP, imP, Bc, Cc, tid, zloc);       // L4 B+C + fused readout
  __syncthreads();

  // ---- reduce + linear head (zpart aliases Bc) ----
  float* zpart = (float*)Bc;         // [8*14]
  float* zbuf  = zpart + 112;        // [14]
#pragma unroll
  for (int w = 0; w < NQ; ++w) {
#pragma unroll
    for (int off = 32; off > 0; off >>= 1)
      zloc[w] += __shfl_down(zloc[w], off, 64);
  }
  const int wave = tid >> 6, lane = tid & 63;
  if (lane == 0) {
#pragma unroll
    for (int w = 0; w < NQ; ++w) zpart[wave * NQ + w] = zloc[w];
  }
  __syncthreads();
  if (tid < NQ) {
    float a = 0.f;
#pragma unroll
    for (int v = 0; v < 8; ++v) a += zpart[v * NQ + tid];
    zbuf[tid] = a;
  }
  __syncthreads();
  if (tid < NCLASSES) {
    float acc = fcb[tid];
#pragma unroll
    for (int w = 0; w < NQ; ++w) acc = fmaf(zbuf[w], fcw[tid * NQ + w], acc);
    out[b * NCLASSES + tid] = acc;
  }
}

extern "C" void kernel_launch(void* const* d_in, const int* in_sizes, int n_in,
                              void* d_out, int out_size, void* d_ws, size_t ws_size,
                              hipStream_t stream) {
  const float* x   = (const float*)d_in[0];
  const float* qp  = (const float*)d_in[1];
  const float* fcw = (const float*)d_in[2];
  const float* fcb = (const float*)d_in[3];
  float* out = (float*)d_out;
  const int B = in_sizes[0] / NQ;

  const size_t shmem = (size_t)(2 * 16384 + 2048 + 768) * sizeof(f16)
                     + (size_t)(56 + 56 + 14 + 14) * sizeof(float);   // 71728 B
  (void)hipFuncSetAttribute((const void*)qsim_kernel,
                            hipFuncAttributeMaxDynamicSharedMemorySize, (int)shmem);
  qsim_kernel<<<B, BLOCK, shmem, stream>>>(x, qp, fcw, fcb, out);
}

// Round 2
// 120.452 us; speedup vs baseline: 1.1697x; 1.0194x over previous
//
#include <hip/hip_runtime.h>
#include <hip/hip_fp16.h>
#include <math.h>

// 14-qubit batched statevector sim, MFMA engine. R12 = R11 (73.6 us kernel) +
// barrier-phase restructure; all layouts/arithmetic byte-identical to R11:
//   1) Builds folded into passes: double-buffered Bc (Bc0/Bc1); a pass reading
//      Bc_cur builds Bc_alt for the next pass between its own barriers. Cc
//      needs no double buffer (its reader finished at the previous trailing
//      sync). Deletes the 7 dedicated build barrier-phases.
//   2) Internal sync moved: state A-frags hoisted into registers BEFORE the
//      in-pass __syncthreads (the read-before-in-place-write invariant only
//      needs loads done at the barrier). Waves now reach the barrier after
//      ~14 ds_reads instead of after the full MFMA+cvt chain; compute->store
//      free-flows to the trailing sync. superBC<FINAL> (no stores) drops its
//      internal sync entirely.
//
// Layouts kept from R7/R8/R11 (verified):
//   F32: phys = t*512 + ((128*(k>>3) + 8*mlow + (k&7)) ^ swz(t))
//   B-planes octet-major: re at 256*(k>>3)+8*n+(k&7), im at +1024.
//   C-planes (A-frag order): UCr at 16*r+k, UCi at +256, -UCi at +512.
//   Superpass store: pS = (8q+2j+h)*512 + 128*(wave>>1)+4*(wave&1)
//                         + 8*(cc ^ (2j+h) ^ q), wrap CNOT(13,0) in v_perm sel.
// LDS: 65536 state + 2*4096 Bc + 1536 Cc + 560 angles = 75824 B (2 blocks/CU).

#define NQ 14
#define NLAYERS 4
#define NCLASSES 10
#define BLOCK 512

typedef _Float16 f16;
typedef _Float16 f16x2 __attribute__((ext_vector_type(2)));
typedef _Float16 f16x4 __attribute__((ext_vector_type(4)));
typedef _Float16 f16x8 __attribute__((ext_vector_type(8)));
typedef float f32x4 __attribute__((ext_vector_type(4)));
typedef unsigned int u32;
typedef u32 u32x2 __attribute__((ext_vector_type(2)));

__device__ __forceinline__ f32x4 mf(f16x8 a, f16x8 b, f32x4 c) {
  return __builtin_amdgcn_mfma_f32_16x16x32_f16(a, b, c, 0, 0, 0);
}
__device__ __forceinline__ f32x4 mf16(f16x4 a, f16x4 b, f32x4 c) {
  return __builtin_amdgcn_mfma_f32_16x16x16f16(a, b, c, 0, 0, 0);
}
__device__ __forceinline__ int swz(int t) { return ((t ^ (t >> 3)) & 7) << 3; }

// packed f32x4 -> f16x4 (2x v_cvt_pkrtz_f16_f32)
__device__ __forceinline__ f16x4 cvt4(f32x4 v) {
  u32x2 r;
  r[0] = __builtin_bit_cast(u32, __builtin_amdgcn_cvt_pkrtz(v[0], v[1]));
  r[1] = __builtin_bit_cast(u32, __builtin_amdgcn_cvt_pkrtz(v[2], v[3]));
  return __builtin_bit_cast(f16x4, r);
}
__device__ __forceinline__ u32 dwof(f16x4 v, int k) {
  return __builtin_bit_cast(u32x2, v)[k];
}

__device__ __forceinline__ int finv5(int n) {
  n ^= ((n >> 3) & 1) << 4;
  n ^= ((n >> 2) & 1) << 3;
  n ^= ((n >> 1) & 1) << 2;
  n ^= (n & 1) << 1;
  return n;
}
__device__ __forceinline__ int finv3(int n) {
  n ^= ((n >> 2) & 1) << 3;
  n ^= ((n >> 1) & 1) << 2;
  n ^= (n & 1) << 1;
  return n;
}

// 32x32 U (RX bits0-4 + 4-CNOT chain), pre-split: re plane [0,1024), im [1024,2048).
__device__ __forceinline__ void build32(f16* Bc, const float* qc, const float* qs,
                                        int base, int tid) {
  const float c0 = qc[base], c1 = qc[base+1], c2 = qc[base+2], c3 = qc[base+3], c4 = qc[base+4];
  const float s0 = qs[base], s1 = qs[base+1], s2 = qs[base+2], s3 = qs[base+3], s4 = qs[base+4];
#pragma unroll
  for (int e = tid; e < 1024; e += BLOCK) {
    const int n = e >> 5, k = e & 31;
    const int d = finv5(n) ^ k;
    float mag = ((d & 1) ? s0 : c0) * ((d & 2) ? s1 : c1);
    mag *= ((d & 4) ? s2 : c2) * ((d & 8) ? s3 : c3);
    mag *= ((d & 16) ? s4 : c4);
    const int t = __popc(d) & 3;
    const f16 v = (f16)((t == 1 || t == 2) ? -mag : mag);
    const int p = 256 * (k >> 3) + 8 * n + (k & 7);
    const bool isreal = !(t & 1);
    Bc[p]        = isreal ? v : (f16)0.f;
    Bc[p + 1024] = isreal ? (f16)0.f : v;
  }
}

// 16x16 U_C (RX bits0-3 + 3-chain) in A-frag order [row r'][k]:
// UCr at 16r+k, UCi at +256, -UCi at +512.
__device__ __forceinline__ void buildC2(f16* Cc, const float* qc, const float* qs,
                                        int base, int tid) {
  if (tid < 256) {
    const float c0 = qc[base], c1 = qc[base+1], c2 = qc[base+2], c3 = qc[base+3];
    const float s0 = qs[base], s1 = qs[base+1], s2 = qs[base+2], s3 = qs[base+3];
    const int rp = tid >> 4, k = tid & 15;
    const int d = finv3(rp) ^ k;
    float mag = ((d & 1) ? s0 : c0) * ((d & 2) ? s1 : c1);
    mag *= ((d & 4) ? s2 : c2) * ((d & 8) ? s3 : c3);
    const int t = __popc(d) & 3;
    const f16 v = (f16)((t == 1 || t == 2) ? -mag : mag);
    const bool isreal = !(t & 1);
    const int p = 16 * rp + k;
    Cc[p]       = isreal ? v : (f16)0.f;
    Cc[p + 256] = isreal ? (f16)0.f : v;
    Cc[p + 512] = isreal ? (f16)0.f : (f16)(-v);
  }
}

// A-pass (wires 0-4, no ext ctrl). Loads hoisted above the internal sync;
// builds next-pass B (into BcW) and C (into CcW) in the compute/store phase.
__device__ __forceinline__ void passA(f16* __restrict__ reP, f16* __restrict__ imP,
                                      const f16* __restrict__ BcR,
                                      f16* __restrict__ BcW, int baseB,
                                      f16* __restrict__ CcW, int baseC,
                                      const float* __restrict__ qc,
                                      const float* __restrict__ qs, int tid) {
  const int lane = tid & 63, wave = tid >> 6;
  const int q = lane >> 4, cc = lane & 15;
  const int n0 = cc, n1 = cc | 16;
  const f16x8 br0 = *(const f16x8*)(BcR + 256 * q + 8 * n0);
  const f16x8 bi0 = *(const f16x8*)(BcR + 1024 + 256 * q + 8 * n0);
  const f16x8 br1 = *(const f16x8*)(BcR + 256 * q + 8 * n1);
  const f16x8 bi1 = *(const f16x8*)(BcR + 1024 + 256 * q + 8 * n1);
  f16x8 Ar[4], Ai[4];
#pragma unroll
  for (int i = 0; i < 4; ++i) {
    const int mt = wave * 4 + i;
    const int pA = mt * 512 + ((128 * q + 8 * cc) ^ swz(mt));
    Ar[i] = *(const f16x8*)(reP + pA);
    Ai[i] = *(const f16x8*)(imP + pA);
  }
  __syncthreads();   // all state reads done before in-place permuted writes
  f16x4 outR[8], outI[8];
#pragma unroll
  for (int i = 0; i < 4; ++i) {
    const f16x8 nAi = -Ai[i];
    {
      f32x4 aR = {0.f,0.f,0.f,0.f}, aI = {0.f,0.f,0.f,0.f};
      aR = mf(Ar[i], br0, aR); aR = mf(nAi, bi0, aR);
      aI = mf(Ar[i], bi0, aI); aI = mf(Ai[i], br0, aI);
      outR[i * 2 + 0] = cvt4(aR);
      outI[i * 2 + 0] = cvt4(aI);
    }
    {
      f32x4 aR = {0.f,0.f,0.f,0.f}, aI = {0.f,0.f,0.f,0.f};
      aR = mf(Ar[i], br1, aR); aR = mf(nAi, bi1, aR);
      aI = mf(Ar[i], bi1, aI); aI = mf(Ai[i], br1, aI);
      outR[i * 2 + 1] = cvt4(aR);
      outI[i * 2 + 1] = cvt4(aI);
    }
  }
#pragma unroll
  for (int i = 0; i < 4; ++i) {
    const int mt = wave * 4 + i;
#pragma unroll
    for (int nt = 0; nt < 2; ++nt) {
      const int n5 = nt * 16 + cc;
      const int pS = n5 * 512 +
          ((128 * (2 * (mt & 1) + (q >> 1)) + 8 * (mt >> 1) + 4 * (q & 1)) ^ swz(n5));
      *(f16x4*)(reP + pS) = outR[i * 2 + nt];
      *(f16x4*)(imP + pS) = outI[i * 2 + nt];
    }
  }
  build32(BcW, qc, qs, baseB, tid);
  buildC2(CcW, qc, qs, baseC, tid);
}

// Fused B+C superpass (see R11 header). Loads hoisted above the internal sync;
// non-final builds next-layer A (into BcW). FINAL: no stores -> no internal
// sync, fused readout from the C accumulators.
template<bool FINAL>
__device__ __forceinline__ void superBC(f16* __restrict__ reP, f16* __restrict__ imP,
                                        const f16* __restrict__ BcR,
                                        const f16* __restrict__ Cc,
                                        f16* __restrict__ BcW, int baseB,
                                        const float* __restrict__ qc,
                                        const float* __restrict__ qs,
                                        int tid, float* __restrict__ zloc) {
  const int lane = tid & 63, wave = tid >> 6;
  const int q = lane >> 4, cc = lane & 15;
  int n0 = cc, n1 = cc | 16;
  if (wave >= 4) { n0 ^= 31; n1 ^= 31; }   // ext-ctrl CNOT(4,5): wire4 = mt bit4
  const f16x8 br0 = *(const f16x8*)(BcR + 256 * q + 8 * n0);
  const f16x8 bi0 = *(const f16x8*)(BcR + 1024 + 256 * q + 8 * n0);
  const f16x8 br1 = *(const f16x8*)(BcR + 256 * q + 8 * n1);
  const f16x8 bi1 = *(const f16x8*)(BcR + 1024 + 256 * q + 8 * n1);
  // U_C A-frags, both ext-ctrl(9,10) variants (ctrl = wire9 = half -> row^15)
  const int r0 = 16 * cc + 4 * q, r1 = 16 * (cc ^ 15) + 4 * q;
  const f16x4 ucr0 = *(const f16x4*)(Cc + r0);
  const f16x4 uci0 = *(const f16x4*)(Cc + 256 + r0);
  const f16x4 ucn0 = *(const f16x4*)(Cc + 512 + r0);
  const f16x4 ucr1 = *(const f16x4*)(Cc + r1);
  const f16x4 uci1 = *(const f16x4*)(Cc + 256 + r1);
  const f16x4 ucn1 = *(const f16x4*)(Cc + 512 + r1);
  f16x8 Ar[4], Ai[4];
#pragma unroll
  for (int i = 0; i < 4; ++i) {
    const int mt = wave * 4 + i;
    const int pA = mt * 512 + ((128 * q + 8 * cc) ^ swz(mt));
    Ar[i] = *(const f16x8*)(reP + pA);
    Ai[i] = *(const f16x8*)(imP + pA);
  }
  if constexpr (!FINAL) __syncthreads();   // reads done before in-place writes

  f16x4 accR[4][2], accI[4][2];   // [i][half] (non-final)
  float z0b = 0.f, z1b = 0.f, z9b = 0.f, zA = 0.f, zB = 0.f, pt = 0.f;
#pragma unroll
  for (int i = 0; i < 4; ++i) {
    const f16x8 nAi = -Ai[i];
#pragma unroll
    for (int h = 0; h < 2; ++h) {
      const f16x8 br = h ? br1 : br0;
      const f16x8 bi = h ? bi1 : bi0;
      f32x4 aR = {0.f,0.f,0.f,0.f}, aI = {0.f,0.f,0.f,0.f};
      aR = mf(Ar[i], br, aR); aR = mf(nAi, bi, aR);
      aI = mf(Ar[i], bi, aI); aI = mf(Ai[i], br, aI);
      const f16x4 s1r = cvt4(aR), s1i = cvt4(aI);
      const f16x4 ur = h ? ucr1 : ucr0;
      const f16x4 ui = h ? uci1 : uci0;
      const f16x4 un = h ? ucn1 : ucn0;
      f32x4 cR = {0.f,0.f,0.f,0.f}, cI = {0.f,0.f,0.f,0.f};
      cR = mf16(ur, s1r, cR); cR = mf16(un, s1i, cR);   // UCr*S1r - UCi*S1i
      cI = mf16(ui, s1r, cI); cI = mf16(ur, s1i, cI);   // UCi*S1r + UCr*S1i
      if constexpr (FINAL) {
        // element (wires): 0-1=i bits [+wrap], 2-4=wave bits, 5-8=cc bits,
        // 9=h, 10-11=j bits, 12-13=q bits; wrap: wire0 ^= (q>>1).
        const float p0 = cR[0]*cR[0] + cI[0]*cI[0];
        const float p1 = cR[1]*cR[1] + cI[1]*cI[1];
        const float p2 = cR[2]*cR[2] + cI[2]*cI[2];
        const float p3 = cR[3]*cR[3] + cI[3]*cI[3];
        const float ps = (p0 + p1) + (p2 + p3);
        zA += (p0 - p1) + (p2 - p3);          // Z10 (j bit0)
        zB += (p0 + p1) - (p2 + p3);          // Z11 (j bit1)
        z0b += (i & 1) ? -ps : ps;
        z1b += (i & 2) ? -ps : ps;
        z9b += h ? -ps : ps;
        pt  += ps;
      } else {
        accR[i][h] = cvt4(cR);
        accI[i][h] = cvt4(cI);
      }
    }
  }
  if constexpr (FINAL) {
    zloc[0]  += (q & 2) ? -z0b : z0b;   // wrap CNOT(13,0) sign fold
    zloc[1]  += z1b;
    zloc[2]  += (wave & 1) ? -pt : pt;
    zloc[3]  += (wave & 2) ? -pt : pt;
    zloc[4]  += (wave & 4) ? -pt : pt;
    zloc[5]  += (cc & 1) ? -pt : pt;
    zloc[6]  += (cc & 2) ? -pt : pt;
    zloc[7]  += (cc & 4) ? -pt : pt;
    zloc[8]  += (cc & 8) ? -pt : pt;
    zloc[9]  += z9b;
    zloc[10] += zA;
    zloc[11] += zB;
    zloc[12] += (q & 1) ? -pt : pt;
    zloc[13] += (q & 2) ? -pt : pt;
  } else {
    // run (j,h) = f16x4 over i=0..3 (wires 0-1); wrap CNOT(13,0): lanes with
    // q>=2 swap i0<->i1, i2<->i3 (folded into the v_perm selector).
    const u32 selLo = (q & 2) ? 0x01000504u : 0x05040100u;
    const u32 selHi = (q & 2) ? 0x03020706u : 0x07060302u;
    const int ibase = 128 * (wave >> 1) + 4 * (wave & 1);
#pragma unroll
    for (int h = 0; h < 2; ++h) {
#pragma unroll
      for (int j = 0; j < 4; ++j) {
        const int pS = (8 * q + 2 * j + h) * 512 + ibase +
                       8 * (cc ^ (2 * j + h) ^ q);
        const int dj = j >> 1;
        const u32 sel = (j & 1) ? selHi : selLo;
        u32x2 vr, vi;
        vr[0] = __builtin_amdgcn_perm(dwof(accR[1][h], dj), dwof(accR[0][h], dj), sel);
        vr[1] = __builtin_amdgcn_perm(dwof(accR[3][h], dj), dwof(accR[2][h], dj), sel);
        vi[0] = __builtin_amdgcn_perm(dwof(accI[1][h], dj), dwof(accI[0][h], dj), sel);
        vi[1] = __builtin_amdgcn_perm(dwof(accI[3][h], dj), dwof(accI[2][h], dj), sel);
        *(u32x2*)(reP + pS) = vr;
        *(u32x2*)(imP + pS) = vi;
      }
    }
    build32(BcW, qc, qs, baseB, tid);   // next-layer A unitary, alt buffer
  }
}

__global__ __launch_bounds__(BLOCK, 4) void qsim_kernel(
    const float* __restrict__ x, const float* __restrict__ qp,
    const float* __restrict__ fcw, const float* __restrict__ fcb,
    float* __restrict__ out) {
  extern __shared__ unsigned char smem[];
  f16* reP = (f16*)smem;                    // [16384]
  f16* imP = reP + 16384;                   // [16384]
  f16* Bc0 = imP + 16384;                   // [2048] re+im planes (aliased scratch)
  f16* Bc1 = Bc0 + 2048;                    // [2048] alternate buffer
  f16* Cc  = Bc1 + 2048;                    // [768] U_C A-frag planes
  float* qc = (float*)(Cc + 768);           // [56]
  float* qs = qc + 56;                      // [56]
  float* xc = qs + 56;                      // [14]
  float* xs = xc + 14;                      // [14]

  const int b = blockIdx.x;
  const int tid = threadIdx.x;

  // ---- angles ----
  if (tid < NQ) {
    float sv, cv; sincosf(0.5f * x[b * NQ + tid], &sv, &cv);
    xc[tid] = cv; xs[tid] = sv;
  } else if (tid >= 64 && tid < 64 + NLAYERS * NQ) {
    const int k = tid - 64;
    float sv, cv; sincosf(0.5f * qp[k], &sv, &cv);
    qc[k] = cv; qs[k] = sv;
  }
  __syncthreads();

  // ---- closed-form state at L1-B entry (scratch aliases Bc0) ----
  float* Flo  = (float*)Bc0;        // [32]
  float* psi  = Flo + 32;           // [32]
  float* PsiR = psi + 32;           // [32]
  float* PsiI = PsiR + 32;          // [32]
  if (tid < 32) {
    float f = 1.f;
#pragma unroll
    for (int j = 0; j < 5; ++j) f *= ((tid >> j) & 1) ? xs[5 + j] : xc[5 + j];
    Flo[tid] = f;
  } else if (tid < 64) {
    const int k = tid - 32;
    float f = 1.f;
#pragma unroll
    for (int j = 0; j < 5; ++j) f *= ((k >> j) & 1) ? xs[j] : xc[j];
    psi[k] = f;
  }
  __syncthreads();
  if (tid < 32) {   // Psi = U_L1A * psi
    const float c0 = qc[0], c1 = qc[1], c2 = qc[2], c3 = qc[3], c4 = qc[4];
    const float s0 = qs[0], s1 = qs[1], s2 = qs[2], s3 = qs[3], s4 = qs[4];
    const int a = finv5(tid);
    float ar = 0.f, ai = 0.f;
    for (int k = 0; k < 32; ++k) {
      const int d = a ^ k;
      float mag = ((d & 1) ? s0 : c0) * ((d & 2) ? s1 : c1);
      mag *= ((d & 4) ? s2 : c2) * ((d & 8) ? s3 : c3);
      mag *= ((d & 16) ? s4 : c4);
      mag *= psi[k];
      const int t = __popc(d) & 3;
      if (t == 0) ar += mag; else if (t == 1) ai -= mag;
      else if (t == 2) ar -= mag; else ai += mag;
    }
    PsiR[tid] = ar; PsiI[tid] = ai;
  }
  __syncthreads();
  {  // state at L1-B entry: amp(e = tid*32 + k) -> F32 layout
    float fhi = 1.f;
#pragma unroll
    for (int j = 0; j < 4; ++j) fhi *= ((tid >> j) & 1) ? xs[10 + j] : xc[10 + j];
    const float cr = fhi * PsiR[tid >> 4], ci = fhi * PsiI[tid >> 4];
    const int t = tid >> 4;
    const int sz = swz(t);
    float Fl[32];
#pragma unroll
    for (int j = 0; j < 32; ++j) Fl[j] = Flo[j];
    __syncthreads();   // scratch reads done; Bc0 free for builds
#pragma unroll
    for (int kb = 0; kb < 4; ++kb) {
      f16x8 hr, hi;
#pragma unroll
      for (int j = 0; j < 8; ++j) {
        const float F = Fl[8 * kb + j];
        hr[j] = (f16)(F * cr);
        hi[j] = (f16)(F * ci);
      }
      const int pb = t * 512 + ((128 * kb + 8 * (tid & 15)) ^ sz);
      *(f16x8*)(reP + pb) = hr;
      *(f16x8*)(imP + pb) = hi;
    }
  }
  build32(Bc0, qc, qs, 0 * NQ + 5, tid);    // U(L1-B)
  buildC2(Cc, qc, qs, 0 * NQ + 10, tid);    // U_C(L1)
  __syncthreads();

  // ---- 7 GEMM passes; each builds the next pass's unitaries in-body ----
  // superBC(l) reads Bc0, builds Bc1 = A(l+1); passA(l) reads Bc1, builds
  // Bc0 = B(l) and Cc = C(l). Cc single-buffered: its reader finished at the
  // previous trailing sync.
  superBC<false>(reP, imP, Bc0, Cc, Bc1, 1 * NQ + 0, qc, qs, tid, nullptr);
  __syncthreads();
#pragma unroll
  for (int l = 1; l < NLAYERS; ++l) {
    passA(reP, imP, Bc1, Bc0, l * NQ + 5, Cc, l * NQ + 10, qc, qs, tid);
    __syncthreads();
    if (l < NLAYERS - 1) {
      superBC<false>(reP, imP, Bc0, Cc, Bc1, (l + 1) * NQ + 0, qc, qs, tid, nullptr);
      __syncthreads();
    }
  }

  float zloc[NQ];
#pragma unroll
  for (int w = 0; w < NQ; ++w) zloc[w] = 0.f;
  superBC<true>(reP, imP, Bc0, Cc, nullptr, 0, qc, qs, tid, zloc);  // L4 + readout
  __syncthreads();

  // ---- reduce + linear head (zpart aliases Bc0) ----
  float* zpart = (float*)Bc0;        // [8*14]
  float* zbuf  = zpart + 112;        // [14]
#pragma unroll
  for (int w = 0; w < NQ; ++w) {
#pragma unroll
    for (int off = 32; off > 0; off >>= 1)
      zloc[w] += __shfl_down(zloc[w], off, 64);
  }
  const int wave = tid >> 6, lane = tid & 63;
  if (lane == 0) {
#pragma unroll
    for (int w = 0; w < NQ; ++w) zpart[wave * NQ + w] = zloc[w];
  }
  __syncthreads();
  if (tid < NQ) {
    float a = 0.f;
#pragma unroll
    for (int v = 0; v < 8; ++v) a += zpart[v * NQ + tid];
    zbuf[tid] = a;
  }
  __syncthreads();
  if (tid < NCLASSES) {
    float acc = fcb[tid];
#pragma unroll
    for (int w = 0; w < NQ; ++w) acc = fmaf(zbuf[w], fcw[tid * NQ + w], acc);
    out[b * NCLASSES + tid] = acc;
  }
}

extern "C" void kernel_launch(void* const* d_in, const int* in_sizes, int n_in,
                              void* d_out, int out_size, void* d_ws, size_t ws_size,
                              hipStream_t stream) {
  const float* x   = (const float*)d_in[0];
  const float* qp  = (const float*)d_in[1];
  const float* fcw = (const float*)d_in[2];
  const float* fcb = (const float*)d_in[3];
  float* out = (float*)d_out;
  const int B = in_sizes[0] / NQ;

  const size_t shmem = (size_t)(2 * 16384 + 2 * 2048 + 768) * sizeof(f16)
                     + (size_t)(56 + 56 + 14 + 14) * sizeof(float);   // 75824 B
  (void)hipFuncSetAttribute((const void*)qsim_kernel,
                            hipFuncAttributeMaxDynamicSharedMemorySize, (int)shmem);
  qsim_kernel<<<B, BLOCK, shmem, stream>>>(x, qp, fcw, fcb, out);
}

// Round 3
// 119.636 us; speedup vs baseline: 1.1776x; 1.0068x over previous
//
#include <hip/hip_runtime.h>
#include <hip/hip_fp16.h>
#include <math.h>

// 14-qubit batched statevector sim, MFMA engine. R13 = R12 (73.0 us kernel) +
// unitary hoisting. R12 post-mortem: barrier restructure was neutral -> the
// kernel is issue-/work-bound (VALU 40% + MFMA 25% + DS issue ~= 75-80% of
// slots), so R13 deletes instructions:
//   1) All U-plane builds (depend only on q_params, identical across all 1024
//      blocks) move to a 1-block pre-kernel writing 7 B-planes (2048 f16 ea)
//      + 4 C-planes (512 f16 ea, re+im; the -UCi plane becomes 2 v_xor negs
//      in-register) into the d_ws workspace: 32 KB, L2-resident.
//   2) Main kernel loads MFMA B/C fragments straight from global into
//      registers, prefetched ONE PASS AHEAD in the post-internal-barrier
//      section: the compiler's vmcnt(0) drain before each trailing s_barrier
//      completes them, so the next pass starts with frags already in VGPRs.
//      Bc/Cc LDS buffers, all build VALU (~300/thread) and ~40 scalar f16
//      ds_writes/thread are deleted. qp sincos only for the 5 init angles.
//
// Layouts kept from R7/R8/R11 (verified):
//   F32: phys = t*512 + ((128*(k>>3) + 8*mlow + (k&7)) ^ swz(t))
//   B-planes octet-major: re at 256*(k>>3)+8*n+(k&7), im at +1024.
//   C-planes (A-frag order): UCr at 16*r+k, UCi at +256.
//   Superpass store: pS = (8q+2j+h)*512 + 128*(wave>>1)+4*(wave&1)
//                         + 8*(cc ^ (2j+h) ^ q), wrap CNOT(13,0) in v_perm sel.
// LDS: 65536 state + 512 scratch + 192 angles = 66240 B (2 blocks/CU).

#define NQ 14
#define NLAYERS 4
#define NCLASSES 10
#define BLOCK 512

typedef _Float16 f16;
typedef _Float16 f16x2 __attribute__((ext_vector_type(2)));
typedef _Float16 f16x4 __attribute__((ext_vector_type(4)));
typedef _Float16 f16x8 __attribute__((ext_vector_type(8)));
typedef float f32x4 __attribute__((ext_vector_type(4)));
typedef unsigned int u32;
typedef u32 u32x2 __attribute__((ext_vector_type(2)));

__device__ __forceinline__ f32x4 mf(f16x8 a, f16x8 b, f32x4 c) {
  return __builtin_amdgcn_mfma_f32_16x16x32_f16(a, b, c, 0, 0, 0);
}
__device__ __forceinline__ f32x4 mf16(f16x4 a, f16x4 b, f32x4 c) {
  return __builtin_amdgcn_mfma_f32_16x16x16f16(a, b, c, 0, 0, 0);
}
__device__ __forceinline__ int swz(int t) { return ((t ^ (t >> 3)) & 7) << 3; }

// packed f32x4 -> f16x4 (2x v_cvt_pkrtz_f16_f32)
__device__ __forceinline__ f16x4 cvt4(f32x4 v) {
  u32x2 r;
  r[0] = __builtin_bit_cast(u32, __builtin_amdgcn_cvt_pkrtz(v[0], v[1]));
  r[1] = __builtin_bit_cast(u32, __builtin_amdgcn_cvt_pkrtz(v[2], v[3]));
  return __builtin_bit_cast(f16x4, r);
}
__device__ __forceinline__ u32 dwof(f16x4 v, int k) {
  return __builtin_bit_cast(u32x2, v)[k];
}

__device__ __forceinline__ int finv5(int n) {
  n ^= ((n >> 3) & 1) << 4;
  n ^= ((n >> 2) & 1) << 3;
  n ^= ((n >> 1) & 1) << 2;
  n ^= (n & 1) << 1;
  return n;
}
__device__ __forceinline__ int finv3(int n) {
  n ^= ((n >> 2) & 1) << 3;
  n ^= ((n >> 1) & 1) << 2;
  n ^= (n & 1) << 1;
  return n;
}

// ---------------- pre-kernel: build all U planes once into workspace -------
// gB: 7 planes x 2048 f16 (re [0,1024), im [1024,2048)), pass order
//     {L1B, L2A, L2B, L3A, L3B, L4A, L4B}; plane p: layer l=(p+1)/2,
//     base = 14*l + (p odd ? 0 : 5).
// gC: 4 layers x 512 f16 (UCr at 16r+k, UCi at +256), base = 14*l + 10.
__global__ void qsim_build(const float* __restrict__ qp,
                           f16* __restrict__ gB, f16* __restrict__ gC) {
  __shared__ float qc[NLAYERS * NQ], qs[NLAYERS * NQ];
  const int tid = threadIdx.x;
  if (tid < NLAYERS * NQ) {
    float sv, cv; sincosf(0.5f * qp[tid], &sv, &cv);
    qc[tid] = cv; qs[tid] = sv;
  }
  __syncthreads();
#pragma unroll
  for (int p = 0; p < 7; ++p) {
    const int l = (p + 1) >> 1;
    const int base = 14 * l + ((p & 1) ? 0 : 5);
    const float c0 = qc[base], c1 = qc[base+1], c2 = qc[base+2], c3 = qc[base+3], c4 = qc[base+4];
    const float s0 = qs[base], s1 = qs[base+1], s2 = qs[base+2], s3 = qs[base+3], s4 = qs[base+4];
#pragma unroll
    for (int e = tid; e < 1024; e += BLOCK) {
      const int n = e >> 5, k = e & 31;
      const int d = finv5(n) ^ k;
      float mag = ((d & 1) ? s0 : c0) * ((d & 2) ? s1 : c1);
      mag *= ((d & 4) ? s2 : c2) * ((d & 8) ? s3 : c3);
      mag *= ((d & 16) ? s4 : c4);
      const int t = __popc(d) & 3;
      const f16 v = (f16)((t == 1 || t == 2) ? -mag : mag);
      const int pp = 256 * (k >> 3) + 8 * n + (k & 7);
      const bool isreal = !(t & 1);
      gB[p * 2048 + pp]        = isreal ? v : (f16)0.f;
      gB[p * 2048 + pp + 1024] = isreal ? (f16)0.f : v;
    }
  }
#pragma unroll
  for (int e = tid; e < 1024; e += BLOCK) {
    const int li = e >> 8, rp = (e >> 4) & 15, k = e & 15;
    const int base = 14 * li + 10;
    const float c0 = qc[base], c1 = qc[base+1], c2 = qc[base+2], c3 = qc[base+3];
    const float s0 = qs[base], s1 = qs[base+1], s2 = qs[base+2], s3 = qs[base+3];
    const int d = finv3(rp) ^ k;
    float mag = ((d & 1) ? s0 : c0) * ((d & 2) ? s1 : c1);
    mag *= ((d & 4) ? s2 : c2) * ((d & 8) ? s3 : c3);
    const int t = __popc(d) & 3;
    const f16 v = (f16)((t == 1 || t == 2) ? -mag : mag);
    const bool isreal = !(t & 1);
    const int pp = li * 512 + 16 * rp + k;
    gC[pp]       = isreal ? v : (f16)0.f;
    gC[pp + 256] = isreal ? (f16)0.f : v;
  }
}

// ---------------- per-wave fragment loaders (global, L1/L2-cached) ---------
struct FB { f16x8 br0, bi0, br1, bi1; };
struct FC { f16x4 ur0, ui0, ur1, ui1; };

__device__ __forceinline__ FB loadB(const f16* __restrict__ g, bool ctrl, int tid) {
  const int lane = tid & 63, wave = tid >> 6;
  const int q = lane >> 4, cc = lane & 15;
  int n0 = cc, n1 = cc | 16;
  if (ctrl && wave >= 4) { n0 ^= 31; n1 ^= 31; }   // ext-ctrl CNOT(4,5)
  FB f;
  f.br0 = *(const f16x8*)(g + 256 * q + 8 * n0);
  f.bi0 = *(const f16x8*)(g + 1024 + 256 * q + 8 * n0);
  f.br1 = *(const f16x8*)(g + 256 * q + 8 * n1);
  f.bi1 = *(const f16x8*)(g + 1024 + 256 * q + 8 * n1);
  return f;
}
__device__ __forceinline__ FC loadC(const f16* __restrict__ g, int tid) {
  const int lane = tid & 63;
  const int q = lane >> 4, cc = lane & 15;
  // both ext-ctrl(9,10) variants (ctrl = wire9 = half -> row^15)
  const int r0 = 16 * cc + 4 * q, r1 = 16 * (cc ^ 15) + 4 * q;
  FC f;
  f.ur0 = *(const f16x4*)(g + r0);
  f.ui0 = *(const f16x4*)(g + 256 + r0);
  f.ur1 = *(const f16x4*)(g + r1);
  f.ui1 = *(const f16x4*)(g + 256 + r1);
  return f;
}

// A-pass (wires 0-4, no ext ctrl). Frags arrive pre-loaded in registers;
// prefetches next superBC's B-frags + C-frags right after the internal sync.
__device__ __forceinline__ void passA(f16* __restrict__ reP, f16* __restrict__ imP,
                                      const FB fb,
                                      const f16* __restrict__ gNB,
                                      const f16* __restrict__ gNC,
                                      FB* __restrict__ nextB,
                                      FC* __restrict__ nextC, int tid) {
  const int lane = tid & 63, wave = tid >> 6;
  const int q = lane >> 4, cc = lane & 15;
  f16x8 Ar[4], Ai[4];
#pragma unroll
  for (int i = 0; i < 4; ++i) {
    const int mt = wave * 4 + i;
    const int pA = mt * 512 + ((128 * q + 8 * cc) ^ swz(mt));
    Ar[i] = *(const f16x8*)(reP + pA);
    Ai[i] = *(const f16x8*)(imP + pA);
  }
  __syncthreads();   // all state reads done before in-place permuted writes
  *nextB = loadB(gNB, true, tid);   // drains at trailing barrier
  *nextC = loadC(gNC, tid);
  f16x4 outR[8], outI[8];
#pragma unroll
  for (int i = 0; i < 4; ++i) {
    const f16x8 nAi = -Ai[i];
    {
      f32x4 aR = {0.f,0.f,0.f,0.f}, aI = {0.f,0.f,0.f,0.f};
      aR = mf(Ar[i], fb.br0, aR); aR = mf(nAi, fb.bi0, aR);
      aI = mf(Ar[i], fb.bi0, aI); aI = mf(Ai[i], fb.br0, aI);
      outR[i * 2 + 0] = cvt4(aR);
      outI[i * 2 + 0] = cvt4(aI);
    }
    {
      f32x4 aR = {0.f,0.f,0.f,0.f}, aI = {0.f,0.f,0.f,0.f};
      aR = mf(Ar[i], fb.br1, aR); aR = mf(nAi, fb.bi1, aR);
      aI = mf(Ar[i], fb.bi1, aI); aI = mf(Ai[i], fb.br1, aI);
      outR[i * 2 + 1] = cvt4(aR);
      outI[i * 2 + 1] = cvt4(aI);
    }
  }
#pragma unroll
  for (int i = 0; i < 4; ++i) {
    const int mt = wave * 4 + i;
#pragma unroll
    for (int nt = 0; nt < 2; ++nt) {
      const int n5 = nt * 16 + cc;
      const int pS = n5 * 512 +
          ((128 * (2 * (mt & 1) + (q >> 1)) + 8 * (mt >> 1) + 4 * (q & 1)) ^ swz(n5));
      *(f16x4*)(reP + pS) = outR[i * 2 + nt];
      *(f16x4*)(imP + pS) = outI[i * 2 + nt];
    }
  }
}

// Fused B+C superpass (R11-verified algebra). Frags pre-loaded; non-final
// prefetches next passA's B-frags. FINAL: no stores -> no internal sync,
// fused readout from the C accumulators.
template<bool FINAL>
__device__ __forceinline__ void superBC(f16* __restrict__ reP, f16* __restrict__ imP,
                                        const FB fb, const FC fc,
                                        const f16* __restrict__ gNB,
                                        FB* __restrict__ nextB,
                                        int tid, float* __restrict__ zloc) {
  const int lane = tid & 63, wave = tid >> 6;
  const int q = lane >> 4, cc = lane & 15;
  f16x8 Ar[4], Ai[4];
#pragma unroll
  for (int i = 0; i < 4; ++i) {
    const int mt = wave * 4 + i;
    const int pA = mt * 512 + ((128 * q + 8 * cc) ^ swz(mt));
    Ar[i] = *(const f16x8*)(reP + pA);
    Ai[i] = *(const f16x8*)(imP + pA);
  }
  if constexpr (!FINAL) {
    __syncthreads();               // reads done before in-place writes
    *nextB = loadB(gNB, false, tid);   // drains at trailing barrier
  }
  const f16x4 ucn0 = -fc.ui0, ucn1 = -fc.ui1;   // -UCi planes in-register

  f16x4 accR[4][2], accI[4][2];   // [i][half] (non-final)
  float z0b = 0.f, z1b = 0.f, z9b = 0.f, zA = 0.f, zB = 0.f, pt = 0.f;
#pragma unroll
  for (int i = 0; i < 4; ++i) {
    const f16x8 nAi = -Ai[i];
#pragma unroll
    for (int h = 0; h < 2; ++h) {
      const f16x8 br = h ? fb.br1 : fb.br0;
      const f16x8 bi = h ? fb.bi1 : fb.bi0;
      f32x4 aR = {0.f,0.f,0.f,0.f}, aI = {0.f,0.f,0.f,0.f};
      aR = mf(Ar[i], br, aR); aR = mf(nAi, bi, aR);
      aI = mf(Ar[i], bi, aI); aI = mf(Ai[i], br, aI);
      const f16x4 s1r = cvt4(aR), s1i = cvt4(aI);
      const f16x4 ur = h ? fc.ur1 : fc.ur0;
      const f16x4 ui = h ? fc.ui1 : fc.ui0;
      const f16x4 un = h ? ucn1 : ucn0;
      f32x4 cR = {0.f,0.f,0.f,0.f}, cI = {0.f,0.f,0.f,0.f};
      cR = mf16(ur, s1r, cR); cR = mf16(un, s1i, cR);   // UCr*S1r - UCi*S1i
      cI = mf16(ui, s1r, cI); cI = mf16(ur, s1i, cI);   // UCi*S1r + UCr*S1i
      if constexpr (FINAL) {
        // element (wires): 0-1=i bits [+wrap], 2-4=wave bits, 5-8=cc bits,
        // 9=h, 10-11=j bits, 12-13=q bits; wrap: wire0 ^= (q>>1).
        const float p0 = cR[0]*cR[0] + cI[0]*cI[0];
        const float p1 = cR[1]*cR[1] + cI[1]*cI[1];
        const float p2 = cR[2]*cR[2] + cI[2]*cI[2];
        const float p3 = cR[3]*cR[3] + cI[3]*cI[3];
        const float ps = (p0 + p1) + (p2 + p3);
        zA += (p0 - p1) + (p2 - p3);          // Z10 (j bit0)
        zB += (p0 + p1) - (p2 + p3);          // Z11 (j bit1)
        z0b += (i & 1) ? -ps : ps;
        z1b += (i & 2) ? -ps : ps;
        z9b += h ? -ps : ps;
        pt  += ps;
      } else {
        accR[i][h] = cvt4(cR);
        accI[i][h] = cvt4(cI);
      }
    }
  }
  if constexpr (FINAL) {
    zloc[0]  += (q & 2) ? -z0b : z0b;   // wrap CNOT(13,0) sign fold
    zloc[1]  += z1b;
    zloc[2]  += (wave & 1) ? -pt : pt;
    zloc[3]  += (wave & 2) ? -pt : pt;
    zloc[4]  += (wave & 4) ? -pt : pt;
    zloc[5]  += (cc & 1) ? -pt : pt;
    zloc[6]  += (cc & 2) ? -pt : pt;
    zloc[7]  += (cc & 4) ? -pt : pt;
    zloc[8]  += (cc & 8) ? -pt : pt;
    zloc[9]  += z9b;
    zloc[10] += zA;
    zloc[11] += zB;
    zloc[12] += (q & 1) ? -pt : pt;
    zloc[13] += (q & 2) ? -pt : pt;
  } else {
    // run (j,h) = f16x4 over i=0..3 (wires 0-1); wrap CNOT(13,0): lanes with
    // q>=2 swap i0<->i1, i2<->i3 (folded into the v_perm selector).
    const u32 selLo = (q & 2) ? 0x01000504u : 0x05040100u;
    const u32 selHi = (q & 2) ? 0x03020706u : 0x07060302u;
    const int ibase = 128 * (wave >> 1) + 4 * (wave & 1);
#pragma unroll
    for (int h = 0; h < 2; ++h) {
#pragma unroll
      for (int j = 0; j < 4; ++j) {
        const int pS = (8 * q + 2 * j + h) * 512 + ibase +
                       8 * (cc ^ (2 * j + h) ^ q);
        const int dj = j >> 1;
        const u32 sel = (j & 1) ? selHi : selLo;
        u32x2 vr, vi;
        vr[0] = __builtin_amdgcn_perm(dwof(accR[1][h], dj), dwof(accR[0][h], dj), sel);
        vr[1] = __builtin_amdgcn_perm(dwof(accR[3][h], dj), dwof(accR[2][h], dj), sel);
        vi[0] = __builtin_amdgcn_perm(dwof(accI[1][h], dj), dwof(accI[0][h], dj), sel);
        vi[1] = __builtin_amdgcn_perm(dwof(accI[3][h], dj), dwof(accI[2][h], dj), sel);
        *(u32x2*)(reP + pS) = vr;
        *(u32x2*)(imP + pS) = vi;
      }
    }
  }
}

__global__ __launch_bounds__(BLOCK, 4) void qsim_kernel(
    const float* __restrict__ x, const float* __restrict__ qp,
    const float* __restrict__ fcw, const float* __restrict__ fcb,
    const f16* __restrict__ gB, const f16* __restrict__ gC,
    float* __restrict__ out) {
  extern __shared__ unsigned char smem[];
  f16* reP = (f16*)smem;                    // [16384]
  f16* imP = reP + 16384;                   // [16384]
  float* scratch = (float*)(imP + 16384);   // [128] init scratch / zpart
  float* qc = scratch + 128;                // [8]  (only 0..4 used)
  float* qs = qc + 8;                       // [8]
  float* xc = qs + 8;                       // [16] (only 0..13 used)
  float* xs = xc + 16;                      // [16]

  const int b = blockIdx.x;
  const int tid = threadIdx.x;

  // L1-B / L1-C frags: issue global loads immediately (drain at init barriers)
  FB fb = loadB(gB, true, tid);
  FC fc = loadC(gC, tid);

  // ---- angles ----
  if (tid < NQ) {
    float sv, cv; sincosf(0.5f * x[b * NQ + tid], &sv, &cv);
    xc[tid] = cv; xs[tid] = sv;
  } else if (tid >= 64 && tid < 64 + 5) {
    const int k = tid - 64;
    float sv, cv; sincosf(0.5f * qp[k], &sv, &cv);
    qc[k] = cv; qs[k] = sv;
  }
  __syncthreads();

  // ---- closed-form state at L1-B entry ----
  float* Flo  = scratch;            // [32]
  float* psi  = Flo + 32;           // [32]
  float* PsiR = psi + 32;           // [32]
  float* PsiI = PsiR + 32;          // [32]
  if (tid < 32) {
    float f = 1.f;
#pragma unroll
    for (int j = 0; j < 5; ++j) f *= ((tid >> j) & 1) ? xs[5 + j] : xc[5 + j];
    Flo[tid] = f;
  } else if (tid < 64) {
    const int k = tid - 32;
    float f = 1.f;
#pragma unroll
    for (int j = 0; j < 5; ++j) f *= ((k >> j) & 1) ? xs[j] : xc[j];
    psi[k] = f;
  }
  __syncthreads();
  if (tid < 32) {   // Psi = U_L1A * psi
    const float c0 = qc[0], c1 = qc[1], c2 = qc[2], c3 = qc[3], c4 = qc[4];
    const float s0 = qs[0], s1 = qs[1], s2 = qs[2], s3 = qs[3], s4 = qs[4];
    const int a = finv5(tid);
    float ar = 0.f, ai = 0.f;
    for (int k = 0; k < 32; ++k) {
      const int d = a ^ k;
      float mag = ((d & 1) ? s0 : c0) * ((d & 2) ? s1 : c1);
      mag *= ((d & 4) ? s2 : c2) * ((d & 8) ? s3 : c3);
      mag *= ((d & 16) ? s4 : c4);
      mag *= psi[k];
      const int t = __popc(d) & 3;
      if (t == 0) ar += mag; else if (t == 1) ai -= mag;
      else if (t == 2) ar -= mag; else ai += mag;
    }
    PsiR[tid] = ar; PsiI[tid] = ai;
  }
  __syncthreads();
  {  // state at L1-B entry: amp(e = tid*32 + k) -> F32 layout
    float fhi = 1.f;
#pragma unroll
    for (int j = 0; j < 4; ++j) fhi *= ((tid >> j) & 1) ? xs[10 + j] : xc[10 + j];
    const float cr = fhi * PsiR[tid >> 4], ci = fhi * PsiI[tid >> 4];
    const int t = tid >> 4;
    const int sz = swz(t);
#pragma unroll
    for (int kb = 0; kb < 4; ++kb) {
      f16x8 hr, hi;
#pragma unroll
      for (int j = 0; j < 8; ++j) {
        const float F = Flo[8 * kb + j];
        hr[j] = (f16)(F * cr);
        hi[j] = (f16)(F * ci);
      }
      const int pb = t * 512 + ((128 * kb + 8 * (tid & 15)) ^ sz);
      *(f16x8*)(reP + pb) = hr;
      *(f16x8*)(imP + pb) = hi;
    }
  }
  __syncthreads();

  // ---- 7 GEMM passes; B/C frags stream from global, prefetched 1 ahead ----
  // gB plane order {L1B, L2A, L2B, L3A, L3B, L4A, L4B}: layer l (1..3) has
  // A-plane 2l-1, B-plane 2l.
  FB fbN; FC fcN;
  superBC<false>(reP, imP, fb, fc, gB + 1 * 2048, &fbN, tid, nullptr);
  __syncthreads();
#pragma unroll
  for (int l = 1; l < NLAYERS; ++l) {
    passA(reP, imP, fbN, gB + (2 * l) * 2048, gC + l * 512, &fb, &fc, tid);
    __syncthreads();
    if (l < NLAYERS - 1) {
      superBC<false>(reP, imP, fb, fc, gB + (2 * l + 1) * 2048, &fbN, tid, nullptr);
      __syncthreads();
    }
  }

  float zloc[NQ];
#pragma unroll
  for (int w = 0; w < NQ; ++w) zloc[w] = 0.f;
  superBC<true>(reP, imP, fb, fc, nullptr, nullptr, tid, zloc);  // L4 + readout
  __syncthreads();

  // ---- reduce + linear head (zpart aliases scratch) ----
  float* zpart = scratch;            // [8*14]
  float* zbuf  = zpart + 112;        // [14]
#pragma unroll
  for (int w = 0; w < NQ; ++w) {
#pragma unroll
    for (int off = 32; off > 0; off >>= 1)
      zloc[w] += __shfl_down(zloc[w], off, 64);
  }
  const int wave = tid >> 6, lane = tid & 63;
  if (lane == 0) {
#pragma unroll
    for (int w = 0; w < NQ; ++w) zpart[wave * NQ + w] = zloc[w];
  }
  __syncthreads();
  if (tid < NQ) {
    float a = 0.f;
#pragma unroll
    for (int v = 0; v < 8; ++v) a += zpart[v * NQ + tid];
    zbuf[tid] = a;
  }
  __syncthreads();
  if (tid < NCLASSES) {
    float acc = fcb[tid];
#pragma unroll
    for (int w = 0; w < NQ; ++w) acc = fmaf(zbuf[w], fcw[tid * NQ + w], acc);
    out[b * NCLASSES + tid] = acc;
  }
}

extern "C" void kernel_launch(void* const* d_in, const int* in_sizes, int n_in,
                              void* d_out, int out_size, void* d_ws, size_t ws_size,
                              hipStream_t stream) {
  const float* x   = (const float*)d_in[0];
  const float* qp  = (const float*)d_in[1];
  const float* fcw = (const float*)d_in[2];
  const float* fcb = (const float*)d_in[3];
  float* out = (float*)d_out;
  const int B = in_sizes[0] / NQ;

  f16* gB = (f16*)d_ws;              // 7 * 2048 f16 = 28672 B
  f16* gC = gB + 7 * 2048;           // 4 * 512 f16  =  4096 B (total 32 KB)

  qsim_build<<<1, BLOCK, 0, stream>>>(qp, gB, gC);

  const size_t shmem = (size_t)(2 * 16384) * sizeof(f16)
                     + (size_t)(128 + 8 + 8 + 16 + 16) * sizeof(float);  // 66240 B
  (void)hipFuncSetAttribute((const void*)qsim_kernel,
                            hipFuncAttributeMaxDynamicSharedMemorySize, (int)shmem);
  qsim_kernel<<<B, BLOCK, shmem, stream>>>(x, qp, fcw, fcb, gB, gC, out);
}